// Round 7
// baseline (195.386 us; speedup 1.0000x reference)
//
#include <hip/hip_runtime.h>
#include <hip/hip_bf16.h>

typedef __bf16 bf16;
typedef __bf16 bf16x8 __attribute__((ext_vector_type(8)));
typedef float floatx4 __attribute__((ext_vector_type(4)));

// B=2, T=512, C=8, D=512, H=8, dk=64. M = B*T*C = 8192.
// ws regions (R = 8192*512 bf16 = 8.39 MB): r0 r1 r2 r3 | WT (2 MB) = 35.6 MB
// Chain: wtr -> WT ; gemm_qkv (z=3 merged, 128x128, 8 waves, REG-STAGED
//   dependence-based pipeline): q->r0 (Q, 0.125-scaled, [hd][t][d]),
//   k->r1 (K), v->r2 (V^T via LDS-transpose epilogue) ;
// attn QBLK=64 swapped-QK (r0,r1,r2)->r3 ; gemm_o (same pipeline) -> d_out.
//
// r5/r6 failure root cause (rule #18): raw s_barrier without lgkmcnt(0) lets
// hipcc sink MFMAs (register-only) past the barrier; a wave then reaches the
// barrier with frag ds_reads outstanding, racing other waves' post-barrier
// buffer writes. Fix: EVERY in-loop barrier carries lgkmcnt(0). Counted-vmcnt
// is abandoned entirely: staging is load->reg (issued 3 tiles ahead) ->
// ds_write (1 iter later); the compiler's automatic dependence waits (which
// correctly account for spills and mixed op types) order load->ds_write.
// vmcnt is never drained in-loop, so global loads overlap compute.

union Pack8 { bf16 h[8]; uint4 u; };
union Pack4 { bf16 h[4]; unsigned long long u; };

__device__ __forceinline__ void store_pack8(bf16* dst, float4 a, float4 b) {
    Pack8 p;
    p.h[0] = (bf16)a.x; p.h[1] = (bf16)a.y; p.h[2] = (bf16)a.z; p.h[3] = (bf16)a.w;
    p.h[4] = (bf16)b.x; p.h[5] = (bf16)b.y; p.h[6] = (bf16)b.z; p.h[7] = (bf16)b.w;
    *(uint4*)dst = p.u;
}

// lgkm-drained barrier: reads complete before writers proceed / writes
// visible before readers proceed. vmcnt intentionally NOT drained.
#define BAR_LG asm volatile("s_waitcnt lgkmcnt(0)\n\ts_barrier" ::: "memory")

// ---------------- weight transpose W[K][N] fp32 -> WT[N][K] bf16 -------------
__global__ __launch_bounds__(256) void wtr_kernel(
    const float* __restrict__ Wq, const float* __restrict__ Wk,
    const float* __restrict__ Wv, const float* __restrict__ Wo,
    bf16* __restrict__ WT)
{
    __shared__ float Ts[64][65];
    const int tid = threadIdx.x;
    const int k0 = blockIdx.x * 64;
    const int n0 = blockIdx.y * 64;
    const int z  = blockIdx.z;
    const float* W = (z == 0) ? Wq : (z == 1) ? Wk : (z == 2) ? Wv : Wo;
    bf16* O = WT + (size_t)z * 512 * 512;
    #pragma unroll
    for (int i = 0; i < 16; i++) {
        const int r = i * 4 + (tid >> 6), c = tid & 63;
        Ts[r][c] = W[(size_t)(k0 + r) * 512 + n0 + c];
    }
    __syncthreads();
    #pragma unroll
    for (int i = 0; i < 16; i++) {
        const int a = i * 4 + (tid >> 6), c = tid & 63;
        O[(size_t)(n0 + a) * 512 + k0 + c] = (bf16)Ts[c][a];
    }
}

// ---------------- merged Q/K/V projection GEMM: reg-staged pipeline ----------
// 128x128 tile, BK=32, 8 waves (wave = 32x64, acc[2][4]). Double-buffered.
// Invariant entering iter t: buf(t&1) holds tile t (visible); set((t)&1)^... :
//   set-x holds tile t+2 if t even / set-y if t odd (loaded at iter t-1).
// Iter t: compute(t); issue loads tile t+3 -> other set; BAR_LG;
//   ds_write tile t+2 set -> buf(t&1); BAR_LG.
__global__ __launch_bounds__(512, 4) void gemm_qkv(
    const float* __restrict__ Aq, const float* __restrict__ Ak,
    const float* __restrict__ Av, const bf16* __restrict__ WT,
    const float* __restrict__ Bq, const float* __restrict__ Bk,
    const float* __restrict__ Bv,
    bf16* __restrict__ Oq, bf16* __restrict__ Ok, bf16* __restrict__ Ov)
{
    __shared__ __align__(16) bf16 smem[17408];   // 34816 B (Tsm overlay needs it)
    bf16* Ab0 = smem;            // 128x32 bf16 = 4096 elems each
    bf16* Ab1 = smem + 4096;
    bf16* Bb0 = smem + 8192;
    bf16* Bb1 = smem + 12288;

    const int z = blockIdx.z;
    const float* A    = (z == 0) ? Aq : (z == 1) ? Ak : Av;
    const float* bias = (z == 0) ? Bq : (z == 1) ? Bk : Bv;
    bf16* out         = (z == 0) ? Oq : (z == 1) ? Ok : Ov;
    const bf16* BT = WT + (size_t)z * 262144;
    const float scale = (z == 0) ? 0.125f : 1.0f;

    const int tid  = threadIdx.x;
    const int lane = tid & 63;
    const int wave = tid >> 6;
    const int quad = lane >> 4;
    const int l16  = lane & 15;
    const int mblk = blockIdx.x * 128;
    const int nblk = blockIdx.y * 128;

    const int srow = wave * 16 + (lane >> 2);
    const int scol = (lane & 3) * 8;
    const float* Ag = A + (size_t)(mblk + srow) * 512 + scol;
    const bf16* Bg  = BT + (size_t)(nblk + srow) * 512 + scol;
    const int aoff = srow * 32 + scol;   // per-lane write offset in a buffer

    const int wr = (wave >> 1) * 32;
    const int wc = (wave & 1) * 64;

    floatx4 acc[2][4] = {};

    // prologue: stage tiles 0,1 to LDS; load tile 2 into set-x.
    float4 ax0 = *(const float4*)(Ag);
    float4 ax1 = *(const float4*)(Ag + 4);
    uint4  bx  = *(const uint4*)(Bg);
    store_pack8(Ab0 + aoff, ax0, ax1);
    *(uint4*)(Bb0 + aoff) = bx;
    float4 ay0 = *(const float4*)(Ag + 32);
    float4 ay1 = *(const float4*)(Ag + 36);
    uint4  by  = *(const uint4*)(Bg + 32);
    store_pack8(Ab1 + aoff, ay0, ay1);
    *(uint4*)(Bb1 + aoff) = by;
    ax0 = *(const float4*)(Ag + 64);
    ax1 = *(const float4*)(Ag + 68);
    bx  = *(const uint4*)(Bg + 64);
    BAR_LG;

    #pragma unroll
    for (int t = 0; t < 16; t++) {
        bf16* Ab = (t & 1) ? Ab1 : Ab0;
        bf16* Bb = (t & 1) ? Bb1 : Bb0;
        bf16x8 a[2], b[4];
        #pragma unroll
        for (int mt = 0; mt < 2; mt++)
            a[mt] = *(const bf16x8*)(Ab + (wr + mt * 16 + l16) * 32 + quad * 8);
        #pragma unroll
        for (int nt = 0; nt < 4; nt++)
            b[nt] = *(const bf16x8*)(Bb + (wc + nt * 16 + l16) * 32 + quad * 8);
        #pragma unroll
        for (int mt = 0; mt < 2; mt++)
            #pragma unroll
            for (int nt = 0; nt < 4; nt++)
                acc[mt][nt] = __builtin_amdgcn_mfma_f32_16x16x32_bf16(
                    a[mt], b[nt], acc[mt][nt], 0, 0, 0);
        if (t <= 12) {                 // issue loads tile t+3 -> other set
            const int kL = (t + 3) * 32;
            if (t & 1) {
                ax0 = *(const float4*)(Ag + kL);
                ax1 = *(const float4*)(Ag + kL + 4);
                bx  = *(const uint4*)(Bg + kL);
            } else {
                ay0 = *(const float4*)(Ag + kL);
                ay1 = *(const float4*)(Ag + kL + 4);
                by  = *(const uint4*)(Bg + kL);
            }
        }
        if (t <= 13) {                 // stage tile t+2 into this buffer pair
            BAR_LG;                    // all waves' reads of buf(t) drained
            if (t & 1) {
                store_pack8(Ab + aoff, ay0, ay1);   // compiler waits loads(t-1)
                *(uint4*)(Bb + aoff) = by;
            } else {
                store_pack8(Ab + aoff, ax0, ax1);
                *(uint4*)(Bb + aoff) = bx;
            }
            BAR_LG;                    // writes visible for iter t+2
        }
    }

    if (z != 2) {
        #pragma unroll
        for (int mt = 0; mt < 2; mt++) {
            #pragma unroll
            for (int nt = 0; nt < 4; nt++) {
                const int colg = nblk + wc + nt * 16 + l16;
                const float bb = bias[colg];
                #pragma unroll
                for (int r = 0; r < 4; r++) {
                    const int rowg = mblk + wr + mt * 16 + quad * 4 + r;
                    const float v = (acc[mt][nt][r] + bb) * scale;
                    const int b_ = rowg >> 12;
                    const int t_ = (rowg >> 3) & 511;
                    const int c  = rowg & 7;
                    const int h  = colg >> 6;
                    const int d  = colg & 63;
                    const int hd = b_ * 64 + h * 8 + c;
                    out[((size_t)hd * 512 + t_) * 64 + d] = (bf16)v;
                }
            }
        }
    } else {
        // transpose epilogue through LDS overlay (34816 B = 128x136 bf16)
        __syncthreads();               // full drain before smem reuse
        typedef bf16 TsmRow[136];
        TsmRow* Tsm = (TsmRow*)smem;
        #pragma unroll
        for (int mt = 0; mt < 2; mt++) {
            #pragma unroll
            for (int nt = 0; nt < 4; nt++) {
                const int cl = wc + nt * 16 + l16;
                const float bb = bias[nblk + cl];
                #pragma unroll
                for (int r = 0; r < 4; r++)
                    Tsm[wr + mt * 16 + quad * 4 + r][cl] =
                        (bf16)(acc[mt][nt][r] + bb);
            }
        }
        __syncthreads();
        const int b_ = mblk >> 12;
        const int t0 = (mblk >> 3) & 511;
        #pragma unroll
        for (int ch = tid; ch < 1024; ch += 512) {
            const int col = ch >> 3, c = ch & 7;
            const int h = (nblk + col) >> 6, d = (nblk + col) & 63;
            const int hd = b_ * 64 + h * 8 + c;
            Pack8 lo, hi;
            #pragma unroll
            for (int j = 0; j < 8; j++) lo.h[j] = Tsm[j * 8 + c][col];
            #pragma unroll
            for (int j = 0; j < 8; j++) hi.h[j] = Tsm[(j + 8) * 8 + c][col];
            bf16* dst = out + ((size_t)hd * 64 + d) * 512 + t0;
            *(uint4*)dst = lo.u;
            *(uint4*)(dst + 8) = hi.u;
        }
    }
}

// ---------------- output projection GEMM: reg-staged pipeline ----------------
// Same structure; both operands bf16, one uint4 per operand per lane.
__global__ __launch_bounds__(512, 4) void gemm_o(
    const bf16* __restrict__ A, const bf16* __restrict__ BT,
    const float* __restrict__ bias, float* __restrict__ out)
{
    __shared__ __align__(16) bf16 smem[16384];
    bf16* Ab0 = smem;
    bf16* Ab1 = smem + 4096;
    bf16* Bb0 = smem + 8192;
    bf16* Bb1 = smem + 12288;

    const int tid  = threadIdx.x;
    const int lane = tid & 63;
    const int wave = tid >> 6;
    const int quad = lane >> 4;
    const int l16  = lane & 15;
    const int mblk = blockIdx.x * 128;
    const int nblk = blockIdx.y * 128;

    const int srow = wave * 16 + (lane >> 2);
    const int scol = (lane & 3) * 8;
    const bf16* Ag = A + (size_t)(mblk + srow) * 512 + scol;
    const bf16* Bg = BT + (size_t)(nblk + srow) * 512 + scol;
    const int aoff = srow * 32 + scol;

    const int wr = (wave >> 1) * 32;
    const int wc = (wave & 1) * 64;

    floatx4 acc[2][4] = {};

    uint4 xa = *(const uint4*)(Ag);
    uint4 xb = *(const uint4*)(Bg);
    *(uint4*)(Ab0 + aoff) = xa;
    *(uint4*)(Bb0 + aoff) = xb;
    uint4 ya = *(const uint4*)(Ag + 32);
    uint4 yb = *(const uint4*)(Bg + 32);
    *(uint4*)(Ab1 + aoff) = ya;
    *(uint4*)(Bb1 + aoff) = yb;
    xa = *(const uint4*)(Ag + 64);
    xb = *(const uint4*)(Bg + 64);
    BAR_LG;

    #pragma unroll
    for (int t = 0; t < 16; t++) {
        bf16* Ab = (t & 1) ? Ab1 : Ab0;
        bf16* Bb = (t & 1) ? Bb1 : Bb0;
        bf16x8 a[2], b[4];
        #pragma unroll
        for (int mt = 0; mt < 2; mt++)
            a[mt] = *(const bf16x8*)(Ab + (wr + mt * 16 + l16) * 32 + quad * 8);
        #pragma unroll
        for (int nt = 0; nt < 4; nt++)
            b[nt] = *(const bf16x8*)(Bb + (wc + nt * 16 + l16) * 32 + quad * 8);
        #pragma unroll
        for (int mt = 0; mt < 2; mt++)
            #pragma unroll
            for (int nt = 0; nt < 4; nt++)
                acc[mt][nt] = __builtin_amdgcn_mfma_f32_16x16x32_bf16(
                    a[mt], b[nt], acc[mt][nt], 0, 0, 0);
        if (t <= 12) {
            const int kL = (t + 3) * 32;
            if (t & 1) { xa = *(const uint4*)(Ag + kL); xb = *(const uint4*)(Bg + kL); }
            else       { ya = *(const uint4*)(Ag + kL); yb = *(const uint4*)(Bg + kL); }
        }
        if (t <= 13) {
            BAR_LG;
            if (t & 1) { *(uint4*)(Ab + aoff) = ya; *(uint4*)(Bb + aoff) = yb; }
            else       { *(uint4*)(Ab + aoff) = xa; *(uint4*)(Bb + aoff) = xb; }
            BAR_LG;
        }
    }

    #pragma unroll
    for (int mt = 0; mt < 2; mt++) {
        #pragma unroll
        for (int nt = 0; nt < 4; nt++) {
            const int colg = nblk + wc + nt * 16 + l16;
            const float bb = bias[colg];
            #pragma unroll
            for (int r = 0; r < 4; r++) {
                const int rowg = mblk + wr + mt * 16 + quad * 4 + r;
                out[(size_t)rowg * 512 + colg] = acc[mt][nt][r] + bb;
            }
        }
    }
}

// ---------------- attention: QBLK=64, swapped QK^T (proven round-4) ----------
#define PST 520

__global__ __launch_bounds__(256, 2) void attn_kernel(
    const bf16* __restrict__ Qws, const bf16* __restrict__ Kws,
    const bf16* __restrict__ Vtws, const int* __restrict__ mask,
    bf16* __restrict__ Xws)
{
    __shared__ bf16 Psm[64][PST];
    __shared__ float redM[4][64];
    __shared__ float redS[4][64];
    const int tid  = threadIdx.x;
    const int wave = tid >> 6;
    const int lane = tid & 63;
    const int quad = lane >> 4;
    const int l16  = lane & 15;
    const int s_ = blockIdx.x;
    const int o_ = ((s_ & 7) << 7) | (s_ >> 3);
    const int hd = o_ >> 3;
    const int qt = o_ & 7;
    const int q0 = qt * 64;
    const int b = hd >> 6;
    const int h = (hd >> 3) & 7;
    const int c = hd & 7;

    const bf16* Qh = Qws + (size_t)hd * 512 * 64;
    const bf16* Kh = Kws + (size_t)hd * 512 * 64;
    const int* mp = mask + ((size_t)b * 512 + q0) * 512;

    bf16x8 aq[4][2];
    #pragma unroll
    for (int s = 0; s < 4; s++) {
        aq[s][0] = *(const bf16x8*)(Qh + (size_t)(q0 + s * 16 + l16) * 64 + quad * 8);
        aq[s][1] = *(const bf16x8*)(Qh + (size_t)(q0 + s * 16 + l16) * 64 + 32 + quad * 8);
    }

    floatx4 sv[4][8];
    #pragma unroll
    for (int s = 0; s < 4; s++)
        #pragma unroll
        for (int nt = 0; nt < 8; nt++)
            sv[s][nt] = (floatx4){0.f, 0.f, 0.f, 0.f};

    #pragma unroll
    for (int nt = 0; nt < 8; nt++) {
        const int s0 = wave * 128 + nt * 16;
        bf16x8 bk0 = *(const bf16x8*)(Kh + (size_t)(s0 + l16) * 64 + quad * 8);
        bf16x8 bk1 = *(const bf16x8*)(Kh + (size_t)(s0 + l16) * 64 + 32 + quad * 8);
        #pragma unroll
        for (int s = 0; s < 4; s++) {
            sv[s][nt] = __builtin_amdgcn_mfma_f32_16x16x32_bf16(
                bk0, aq[s][0], sv[s][nt], 0, 0, 0);
            sv[s][nt] = __builtin_amdgcn_mfma_f32_16x16x32_bf16(
                bk1, aq[s][1], sv[s][nt], 0, 0, 0);
        }
    }

    float mx[4] = {-3.0e38f, -3.0e38f, -3.0e38f, -3.0e38f};
    #pragma unroll
    for (int s = 0; s < 4; s++)
        #pragma unroll
        for (int nt = 0; nt < 8; nt++) {
            const int4 mv = *(const int4*)(
                mp + (size_t)(s * 16 + l16) * 512 + wave * 128 + nt * 16 + quad * 4);
            float v0 = sv[s][nt][0] + ((mv.x == 0) ? -1.0e9f : 0.0f);
            float v1 = sv[s][nt][1] + ((mv.y == 0) ? -1.0e9f : 0.0f);
            float v2 = sv[s][nt][2] + ((mv.z == 0) ? -1.0e9f : 0.0f);
            float v3 = sv[s][nt][3] + ((mv.w == 0) ? -1.0e9f : 0.0f);
            sv[s][nt][0] = v0; sv[s][nt][1] = v1;
            sv[s][nt][2] = v2; sv[s][nt][3] = v3;
            mx[s] = fmaxf(mx[s], fmaxf(fmaxf(v0, v1), fmaxf(v2, v3)));
        }
    #pragma unroll
    for (int s = 0; s < 4; s++) {
        mx[s] = fmaxf(mx[s], __shfl_xor(mx[s], 16, 64));
        mx[s] = fmaxf(mx[s], __shfl_xor(mx[s], 32, 64));
    }
    if (quad == 0)
        #pragma unroll
        for (int s = 0; s < 4; s++) redM[wave][s * 16 + l16] = mx[s];
    __syncthreads();

    float mf[4], sum[4] = {0.f, 0.f, 0.f, 0.f};
    #pragma unroll
    for (int s = 0; s < 4; s++) {
        const int qr = s * 16 + l16;
        mf[s] = fmaxf(fmaxf(redM[0][qr], redM[1][qr]),
                      fmaxf(redM[2][qr], redM[3][qr]));
    }
    #pragma unroll
    for (int s = 0; s < 4; s++)
        #pragma unroll
        for (int nt = 0; nt < 8; nt++)
            #pragma unroll
            for (int r = 0; r < 4; r++) {
                const float e = __expf(sv[s][nt][r] - mf[s]);
                sv[s][nt][r] = e;
                sum[s] += e;
            }
    #pragma unroll
    for (int s = 0; s < 4; s++) {
        sum[s] += __shfl_xor(sum[s], 16, 64);
        sum[s] += __shfl_xor(sum[s], 32, 64);
    }
    if (quad == 0)
        #pragma unroll
        for (int s = 0; s < 4; s++) redS[wave][s * 16 + l16] = sum[s];
    __syncthreads();

    float inv[4];
    #pragma unroll
    for (int s = 0; s < 4; s++) {
        const int qr = s * 16 + l16;
        inv[s] = 1.f / (redS[0][qr] + redS[1][qr] + redS[2][qr] + redS[3][qr]);
    }
    #pragma unroll
    for (int s = 0; s < 4; s++)
        #pragma unroll
        for (int nt = 0; nt < 8; nt++) {
            Pack4 pk;
            #pragma unroll
            for (int r = 0; r < 4; r++)
                pk.h[r] = (bf16)(sv[s][nt][r] * inv[s]);
            *(unsigned long long*)&Psm[s * 16 + l16][wave * 128 + nt * 16 + quad * 4]
                = pk.u;
        }
    __syncthreads();

    const bf16* Vh = Vtws + (size_t)hd * 64 * 512;
    const int d0 = wave * 16;
    floatx4 o[4] = {};
    #pragma unroll
    for (int ks = 0; ks < 16; ks++) {
        bf16x8 bv = *(const bf16x8*)(Vh + (size_t)(d0 + l16) * 512 + ks * 32 + quad * 8);
        #pragma unroll
        for (int rt = 0; rt < 4; rt++) {
            bf16x8 ap = *(const bf16x8*)(&Psm[rt * 16 + l16][ks * 32 + quad * 8]);
            o[rt] = __builtin_amdgcn_mfma_f32_16x16x32_bf16(ap, bv, o[rt], 0, 0, 0);
        }
    }
    #pragma unroll
    for (int rt = 0; rt < 4; rt++)
        #pragma unroll
        for (int r = 0; r < 4; r++) {
            const int q = q0 + rt * 16 + quad * 4 + r;
            const size_t row = ((size_t)b * 512 + q) * 8 + c;
            Xws[row * 512 + h * 64 + d0 + l16] = (bf16)o[rt][r];
        }
}

extern "C" void kernel_launch(void* const* d_in, const int* in_sizes, int n_in,
                              void* d_out, int out_size, void* d_ws, size_t ws_size,
                              hipStream_t stream)
{
    const float* qin  = (const float*)d_in[0];
    const float* kin  = (const float*)d_in[1];
    const float* vin  = (const float*)d_in[2];
    const int*   mask = (const int*)d_in[3];
    const float* Bq = (const float*)d_in[5];
    const float* Bk = (const float*)d_in[7];
    const float* Bv = (const float*)d_in[9];
    const float* Bo = (const float*)d_in[11];
    float* out = (float*)d_out;

    const size_t R = (size_t)8192 * 512;
    bf16* r0 = (bf16*)d_ws;
    bf16* r1 = r0 + R;
    bf16* r2 = r1 + R;
    bf16* r3 = r2 + R;
    bf16* WT = r3 + R;

    wtr_kernel<<<dim3(8, 8, 4), dim3(256), 0, stream>>>(
        (const float*)d_in[4], (const float*)d_in[6],
        (const float*)d_in[8], (const float*)d_in[10], WT);
    gemm_qkv<<<dim3(64, 4, 3), dim3(512), 0, stream>>>(
        qin, kin, vin, WT, Bq, Bk, Bv, r0, r1, r2);
    attn_kernel<<<dim3(1024), dim3(256), 0, stream>>>(
        r0, r1, r2, mask, r3);
    gemm_o<<<dim3(64, 4), dim3(512), 0, stream>>>(
        r3, WT + (size_t)3 * 262144, Bo, out);
}